// Round 8
// baseline (207.189 us; speedup 1.0000x reference)
//
#include <hip/hip_runtime.h>
#include <hip/hip_bf16.h>

#define E_N 4
#define B_N 64
#define IN_N 4096
#define H_N 4096
#define R_N 512
#define OUT_N 4096
#define TOT_N 8388608  // R*IN + H*R + R*H + OUT*R

typedef float f32x4 __attribute__((ext_vector_type(4)));
typedef short bf16x8 __attribute__((ext_vector_type(8)));
typedef unsigned short u16x8 __attribute__((ext_vector_type(8)));

__device__ __forceinline__ unsigned short f2bf_bits(float f) {
    return __builtin_bit_cast(unsigned short, __float2bfloat16(f));
}
__device__ __forceinline__ float bfbits2f(unsigned short u) {
    return __builtin_bit_cast(float, ((unsigned)u) << 16);
}

__device__ __forceinline__ void stage16(const void* g, void* l) {
    __builtin_amdgcn_global_load_lds(
        (const __attribute__((address_space(1))) void*)g,
        (__attribute__((address_space(3))) void*)l, 16, 0, 0);
}

// C[e,b,n] = sum_k A[e?,b,k] * (W[n,k] + D[e,n,k])
// Block: 256 thr / 4 waves, tile 64 rows x 32 cols, KCH=512 in 8 K-tiles of 64.
// R6 double-buffered staging body (best verified: 51.4 us).
// MODE 0: direct bf16 output (optional relu).
// MODE 1: f32 partials + fused split-K reduce (last block of KS-group sums
//         ks-ascending -> bf16 H). Bit-identical to the old reduce_ks kernel.
// MODE 2: f32 partials + fused expert reduce (last block of E-group applies
//         scores e-ascending -> f32 out). Bit-identical to old reduce_experts.
template<int K_TOT, int N_TOT, int KS, bool A_SHARED, bool RELU, int MODE>
__global__ __launch_bounds__(256, 2)
void gemm_layer(const __hip_bfloat16* __restrict__ A, const float* __restrict__ W,
                const float* __restrict__ D, float* __restrict__ OutF,
                __hip_bfloat16* __restrict__ OutB, int* __restrict__ counters,
                const float* __restrict__ scores, float* __restrict__ finalOut)
{
    constexpr int KCH = K_TOT / KS;      // 512 for every layer
    constexpr int NT = N_TOT / 32;
    constexpr int NTILES = KCH / 64;     // 8
    constexpr int BUFSZ = 24576;
    __shared__ __align__(16) char smem[2 * BUFSZ];  // [buf][ Wt 8K | Dt 8K | At 8K ]
    __shared__ int lastFlag;

    const int bid = blockIdx.x;
    const int ks = bid % KS;
    const int nt = (bid / KS) % NT;
    const int e  = bid / (KS * NT);
    const int tid = threadIdx.x;
    const int l  = tid & 63;
    const int w  = tid >> 6;
    const int wn = w & 1;
    const int wm = w >> 1;
    const int lr = l & 15;
    const int lk = (l >> 4) << 3;

    const float* Wb = W + (size_t)(nt * 32) * K_TOT + ks * KCH;
    const float* Db = D + (size_t)e * TOT_N + (size_t)(nt * 32) * K_TOT + ks * KCH;
    const __hip_bfloat16* Ab = A + (A_SHARED ? (size_t)0 : (size_t)e * B_N * K_TOT)
                                 + ks * KCH;

    const char* gsrc[6];
    int loff[6];
    int kstep[6];
    #pragma unroll
    for (int i = 0; i < 6; ++i) {
        const int q = w * 6 + i;
        if (q < 8) {
            const int off = q * 1024 + l * 16;
            const int row = off >> 8;
            const int kb  = off & 255;
            gsrc[i] = (const char*)(Wb + (size_t)row * K_TOT) + (kb ^ ((row & 7) << 4));
            loff[i] = q * 1024;
            kstep[i] = 4;
        } else if (q < 16) {
            const int c = q - 8;
            const int off = c * 1024 + l * 16;
            const int row = off >> 8;
            const int kb  = off & 255;
            gsrc[i] = (const char*)(Db + (size_t)row * K_TOT) + (kb ^ ((row & 7) << 4));
            loff[i] = 8192 + c * 1024;
            kstep[i] = 4;
        } else {
            const int c = q - 16;
            const int off = c * 1024 + l * 16;
            const int row = off >> 7;
            const int kb  = off & 127;
            gsrc[i] = (const char*)(Ab + (size_t)row * K_TOT) + (kb ^ ((row & 7) << 4));
            loff[i] = 16384 + c * 1024;
            kstep[i] = 2;
        }
    }

    f32x4 acc[2] = {};
    const int wrow = wn * 16 + lr;
    const int wswz = (wrow & 7) << 4;
    const int arow0 = wm * 32 + lr;
    const int aswz = (arow0 & 7) << 4;

    #pragma unroll
    for (int i = 0; i < 6; ++i)
        stage16(gsrc[i], smem + loff[i]);
    __syncthreads();

    for (int t = 0; t < NTILES; ++t) {
        if (t + 1 < NTILES) {
            const int kk = (t + 1) * 64;
            char* b = smem + ((t + 1) & 1) * BUFSZ;
            #pragma unroll
            for (int i = 0; i < 6; ++i)
                stage16(gsrc[i] + kk * kstep[i], b + loff[i]);
        }

        const char* buf = smem + (t & 1) * BUFSZ;
        #pragma unroll
        for (int inner = 0; inner < 2; ++inner) {
            const int b0 = (inner * 32 + lk) * 4;
            const char* wrp = buf + wrow * 256;
            const char* drp = buf + 8192 + wrow * 256;
            f32x4 w0 = *(const f32x4*)(wrp + ((b0)      ^ wswz));
            f32x4 w1 = *(const f32x4*)(wrp + ((b0 + 16) ^ wswz));
            f32x4 d0 = *(const f32x4*)(drp + ((b0)      ^ wswz));
            f32x4 d1 = *(const f32x4*)(drp + ((b0 + 16) ^ wswz));
            f32x4 s0 = w0 + d0;
            f32x4 s1 = w1 + d1;
            bf16x8 bhi, blo;
            #pragma unroll
            for (int j = 0; j < 4; ++j) {
                unsigned short h0 = f2bf_bits(s0[j]);
                bhi[j] = (short)h0;
                blo[j] = (short)f2bf_bits(s0[j] - bfbits2f(h0));
                unsigned short h1 = f2bf_bits(s1[j]);
                bhi[j + 4] = (short)h1;
                blo[j + 4] = (short)f2bf_bits(s1[j] - bfbits2f(h1));
            }
            const int ab = (inner * 32 + lk) * 2;
            #pragma unroll
            for (int mf = 0; mf < 2; ++mf) {
                const int ar = arow0 + mf * 16;
                const char* arp = buf + 16384 + ar * 128;
                bf16x8 af = *(const bf16x8*)(arp + (ab ^ aswz));
                acc[mf] = __builtin_amdgcn_mfma_f32_16x16x32_bf16(af, bhi, acc[mf], 0, 0, 0);
                acc[mf] = __builtin_amdgcn_mfma_f32_16x16x32_bf16(af, blo, acc[mf], 0, 0, 0);
            }
        }
        __syncthreads();
    }

    // C/D layout: col = l&15 (== nrow), row(frag) = (l>>4)*4 + i
    const int rb = (l >> 4) * 4;
    const int nrow = nt * 32 + wrow;
    #pragma unroll
    for (int j = 0; j < 2; ++j) {
        #pragma unroll
        for (int i = 0; i < 4; ++i) {
            const int row = wm * 32 + j * 16 + rb + i;
            float v = acc[j][i];
            if (RELU) v = fmaxf(v, 0.0f);
            if (MODE == 0) {
                OutB[(size_t)e * B_N * N_TOT + (size_t)row * N_TOT + nrow] =
                    __float2bfloat16(v);
            } else {
                OutF[(size_t)(e * KS + ks) * B_N * N_TOT + (size_t)row * N_TOT + nrow] = v;
            }
        }
    }

    if (MODE == 0) return;

    // ---- fused reduction: last block of the group reduces its slice ----
    __threadfence();   // release partials to device scope (across XCD L2s)
    if (tid == 0) {
        const int g    = (MODE == 1) ? (bid / KS) : nt;
        const int need = (MODE == 1) ? KS : E_N;
        lastFlag = (atomicAdd(&counters[g], 1) == need - 1);
    }
    __syncthreads();
    if (!lastFlag) return;

    const int row = tid >> 2;          // 0..63
    const int c0  = (tid & 3) * 8;     // 0,8,16,24  -> 8 cols each
    const int col = nt * 32 + c0;

    if (MODE == 1) {
        // H[e,b,col..col+8) = bf16( sum_ks P[e,ks,b,col..] ), ks ascending
        const float* base = OutF + (size_t)(e * KS) * B_N * N_TOT
                                 + (size_t)row * N_TOT + col;
        f32x4 s0 = {}, s1 = {};
        #pragma unroll
        for (int k = 0; k < KS; ++k) {
            const float* p = base + (size_t)k * B_N * N_TOT;
            s0 += *(const f32x4*)(p);
            s1 += *(const f32x4*)(p + 4);
        }
        u16x8 o;
        #pragma unroll
        for (int j = 0; j < 4; ++j) {
            o[j]     = f2bf_bits(s0[j]);
            o[j + 4] = f2bf_bits(s1[j]);
        }
        *(u16x8*)(OutB + (size_t)e * B_N * N_TOT + (size_t)row * N_TOT + col) = o;
    } else {
        // out[b,col..] = sum_e scores[e] * P[e,b,col..], e ascending
        const float* base = OutF + (size_t)row * N_TOT + col;
        f32x4 a0 = {}, a1 = {};
        #pragma unroll
        for (int e2 = 0; e2 < E_N; ++e2) {
            const float s = scores[e2];
            const float* p = base + (size_t)e2 * B_N * N_TOT;
            a0 += s * *(const f32x4*)(p);
            a1 += s * *(const f32x4*)(p + 4);
        }
        float* op = finalOut + (size_t)row * N_TOT + col;
        *(f32x4*)(op)     = a0;
        *(f32x4*)(op + 4) = a1;
    }
}

// xb = bf16(x) — 2 f32 / thread, 512 blocks
__global__ __launch_bounds__(256)
void convert_bf16(const float* __restrict__ X, __hip_bfloat16* __restrict__ Xb)
{
    const int gt = blockIdx.x * 256 + threadIdx.x;
    const int idx = gt * 2;
    const float2 v = *(const float2*)(X + idx);
    const unsigned u = ((unsigned)f2bf_bits(v.y) << 16) | f2bf_bits(v.x);
    *(unsigned*)((char*)Xb + (size_t)idx * 2) = u;
}

extern "C" void kernel_launch(void* const* d_in, const int* in_sizes, int n_in,
                              void* d_out, int out_size, void* d_ws, size_t ws_size,
                              hipStream_t stream)
{
    const float* x      = (const float*)d_in[0];
    const float* scores = (const float*)d_in[1];
    const float* delta  = (const float*)d_in[2];
    const float* W1     = (const float*)d_in[3];
    const float* W2     = (const float*)d_in[4];
    const float* W3     = (const float*)d_in[5];
    const float* W4     = (const float*)d_in[6];
    float* out = (float*)d_out;

    char* ws = (char*)d_ws;
    __hip_bfloat16* xb  = (__hip_bfloat16*)(ws);                    // 512 KB
    __hip_bfloat16* h1b = (__hip_bfloat16*)(ws + 524288);           // 256 KB
    __hip_bfloat16* h2b = (__hip_bfloat16*)(ws + 786432);           // 2 MB
    __hip_bfloat16* h3b = (__hip_bfloat16*)(ws + 2883584);          // 256 KB
    float* P1 = (float*)(ws + 3145728);                             // 4 MB
    float* P3 = (float*)(ws + 7340032);                             // 4 MB
    float* P4 = (float*)(ws + 11534336);                            // 4 MB
    int* cnt  = (int*)(ws + 15728640);                              // 1 KB (256 ints)

    const float* d1 = delta;
    const float* d2 = d1 + (size_t)R_N * IN_N;
    const float* d3 = d2 + (size_t)H_N * R_N;
    const float* d4 = d3 + (size_t)R_N * H_N;

    // zero the group counters (L1: 64, L3: 64, L4: 128)
    hipMemsetAsync(cnt, 0, 1024, stream);

    convert_bf16<<<dim3(B_N * IN_N / 2 / 256), dim3(256), 0, stream>>>(x, xb);

    // L1: K=4096, N=512, KS=8, fused split-K reduce -> h1b
    gemm_layer<IN_N, R_N, 8, true, false, 1>
        <<<dim3(E_N * (R_N / 32) * 8), dim3(256), 0, stream>>>(
            xb, W1, d1, P1, h1b, cnt, nullptr, nullptr);

    // L2: K=512, N=4096, relu -> bf16 direct
    gemm_layer<R_N, H_N, 1, false, true, 0>
        <<<dim3(E_N * (H_N / 32)), dim3(256), 0, stream>>>(
            h1b, W2, d2, nullptr, h2b, nullptr, nullptr, nullptr);

    // L3: K=4096, N=512, KS=8, fused split-K reduce -> h3b
    gemm_layer<H_N, R_N, 8, false, false, 1>
        <<<dim3(E_N * (R_N / 32) * 8), dim3(256), 0, stream>>>(
            h2b, W3, d3, P3, h3b, cnt + 64, nullptr, nullptr);

    // L4: K=512, N=4096, fused expert reduce (scores) -> out
    gemm_layer<R_N, OUT_N, 1, false, false, 2>
        <<<dim3(E_N * (OUT_N / 32)), dim3(256), 0, stream>>>(
            h3b, W4, d4, P4, nullptr, cnt + 128, scores, out);
}

// Round 10
// 63.818 us; speedup vs baseline: 3.2466x; 3.2466x over previous
//
#include <hip/hip_runtime.h>
#include <hip/hip_bf16.h>

#define E_N 4
#define B_N 64
#define IN_N 4096
#define H_N 4096
#define R_N 512
#define OUT_N 4096
#define TOT_N 8388608  // R*IN + H*R + R*H + OUT*R

typedef float f32x4 __attribute__((ext_vector_type(4)));
typedef short bf16x8 __attribute__((ext_vector_type(8)));

__device__ __forceinline__ unsigned short f2bf_bits(float f) {
    return __builtin_bit_cast(unsigned short, __float2bfloat16(f));
}
__device__ __forceinline__ float bfbits2f(unsigned short u) {
    return __builtin_bit_cast(float, ((unsigned)u) << 16);
}

__device__ __forceinline__ void stage16(const void* g, void* l) {
    __builtin_amdgcn_global_load_lds(
        (const __attribute__((address_space(1))) void*)g,
        (__attribute__((address_space(3))) void*)l, 16, 0, 0);
}

// ---------------- R6 gemm (layers 1-3): best verified body, unchanged ----------------
// C[e,b,n] = sum_k A[e?,b,k] * (W[n,k] + D[e,n,k])
template<int K_TOT, int N_TOT, int KS, bool A_SHARED, bool RELU, bool OUT_BF16>
__global__ __launch_bounds__(256, 2)
void gemm_layer(const __hip_bfloat16* __restrict__ A, const float* __restrict__ W,
                const float* __restrict__ D, float* __restrict__ OutF,
                __hip_bfloat16* __restrict__ OutB)
{
    constexpr int KCH = K_TOT / KS;
    constexpr int NT = N_TOT / 32;
    constexpr int NTILES = KCH / 64;
    constexpr int BUFSZ = 24576;
    __shared__ __align__(16) char smem[2 * BUFSZ];

    const int bid = blockIdx.x;
    const int ks = bid % KS;
    const int nt = (bid / KS) % NT;
    const int e  = bid / (KS * NT);
    const int tid = threadIdx.x;
    const int l  = tid & 63;
    const int w  = tid >> 6;
    const int wn = w & 1;
    const int wm = w >> 1;
    const int lr = l & 15;
    const int lk = (l >> 4) << 3;

    const float* Wb = W + (size_t)(nt * 32) * K_TOT + ks * KCH;
    const float* Db = D + (size_t)e * TOT_N + (size_t)(nt * 32) * K_TOT + ks * KCH;
    const __hip_bfloat16* Ab = A + (A_SHARED ? (size_t)0 : (size_t)e * B_N * K_TOT)
                                 + ks * KCH;

    const char* gsrc[6];
    int loff[6];
    int kstep[6];
    #pragma unroll
    for (int i = 0; i < 6; ++i) {
        const int q = w * 6 + i;
        if (q < 8) {
            const int off = q * 1024 + l * 16;
            const int row = off >> 8;
            const int kb  = off & 255;
            gsrc[i] = (const char*)(Wb + (size_t)row * K_TOT) + (kb ^ ((row & 7) << 4));
            loff[i] = q * 1024;
            kstep[i] = 4;
        } else if (q < 16) {
            const int c = q - 8;
            const int off = c * 1024 + l * 16;
            const int row = off >> 8;
            const int kb  = off & 255;
            gsrc[i] = (const char*)(Db + (size_t)row * K_TOT) + (kb ^ ((row & 7) << 4));
            loff[i] = 8192 + c * 1024;
            kstep[i] = 4;
        } else {
            const int c = q - 16;
            const int off = c * 1024 + l * 16;
            const int row = off >> 7;
            const int kb  = off & 127;
            gsrc[i] = (const char*)(Ab + (size_t)row * K_TOT) + (kb ^ ((row & 7) << 4));
            loff[i] = 16384 + c * 1024;
            kstep[i] = 2;
        }
    }

    f32x4 acc[2] = {};
    const int wrow = wn * 16 + lr;
    const int wswz = (wrow & 7) << 4;
    const int arow0 = wm * 32 + lr;
    const int aswz = (arow0 & 7) << 4;

    #pragma unroll
    for (int i = 0; i < 6; ++i)
        stage16(gsrc[i], smem + loff[i]);
    __syncthreads();

    for (int t = 0; t < NTILES; ++t) {
        if (t + 1 < NTILES) {
            const int kk = (t + 1) * 64;
            char* b = smem + ((t + 1) & 1) * BUFSZ;
            #pragma unroll
            for (int i = 0; i < 6; ++i)
                stage16(gsrc[i] + kk * kstep[i], b + loff[i]);
        }

        const char* buf = smem + (t & 1) * BUFSZ;
        #pragma unroll
        for (int inner = 0; inner < 2; ++inner) {
            const int b0 = (inner * 32 + lk) * 4;
            const char* wrp = buf + wrow * 256;
            const char* drp = buf + 8192 + wrow * 256;
            f32x4 w0 = *(const f32x4*)(wrp + ((b0)      ^ wswz));
            f32x4 w1 = *(const f32x4*)(wrp + ((b0 + 16) ^ wswz));
            f32x4 d0 = *(const f32x4*)(drp + ((b0)      ^ wswz));
            f32x4 d1 = *(const f32x4*)(drp + ((b0 + 16) ^ wswz));
            f32x4 s0 = w0 + d0;
            f32x4 s1 = w1 + d1;
            bf16x8 bhi, blo;
            #pragma unroll
            for (int j = 0; j < 4; ++j) {
                unsigned short h0 = f2bf_bits(s0[j]);
                bhi[j] = (short)h0;
                blo[j] = (short)f2bf_bits(s0[j] - bfbits2f(h0));
                unsigned short h1 = f2bf_bits(s1[j]);
                bhi[j + 4] = (short)h1;
                blo[j + 4] = (short)f2bf_bits(s1[j] - bfbits2f(h1));
            }
            const int ab = (inner * 32 + lk) * 2;
            #pragma unroll
            for (int mf = 0; mf < 2; ++mf) {
                const int ar = arow0 + mf * 16;
                const char* arp = buf + 16384 + ar * 128;
                bf16x8 af = *(const bf16x8*)(arp + (ab ^ aswz));
                acc[mf] = __builtin_amdgcn_mfma_f32_16x16x32_bf16(af, bhi, acc[mf], 0, 0, 0);
                acc[mf] = __builtin_amdgcn_mfma_f32_16x16x32_bf16(af, blo, acc[mf], 0, 0, 0);
            }
        }
        __syncthreads();
    }

    const int rb = (l >> 4) * 4;
    const int nrow = nt * 32 + wrow;
    #pragma unroll
    for (int j = 0; j < 2; ++j) {
        #pragma unroll
        for (int i = 0; i < 4; ++i) {
            const int row = wm * 32 + j * 16 + rb + i;
            float v = acc[j][i];
            if (RELU) v = fmaxf(v, 0.0f);
            if (OUT_BF16) {
                OutB[(size_t)e * B_N * N_TOT + (size_t)row * N_TOT + nrow] =
                    __float2bfloat16(v);
            } else {
                OutF[(size_t)(e * KS + ks) * B_N * N_TOT + (size_t)row * N_TOT + nrow] = v;
            }
        }
    }
}

// ---------------- L4: e-as-K fused expert combine ----------------
// out[b,o] = sum_{k=0..2047} h3s[b,k] * (W4[o,k&511] + d4[k>>9][o,k&511])
// where h3s[b, e*512+r] = scores[e]*bf16(h3[e,b,r]).  128 blocks (NT=128).
// NOTE: delta's expert stride is TOT_N (layout (E, TOT)), not OUT_N*R_N.
__global__ __launch_bounds__(256, 2)
void gemm_l4(const __hip_bfloat16* __restrict__ A, const float* __restrict__ W,
             const float* __restrict__ D, float* __restrict__ Out)
{
    constexpr int KT = E_N * R_N;        // 2048
    constexpr int NTILES = KT / 64;      // 32
    constexpr int BUFSZ = 24576;
    __shared__ __align__(16) char smem[2 * BUFSZ];

    const int nt = blockIdx.x;           // 0..127
    const int tid = threadIdx.x;
    const int l  = tid & 63;
    const int w  = tid >> 6;
    const int wn = w & 1;
    const int wm = w >> 1;
    const int lr = l & 15;
    const int lk = (l >> 4) << 3;

    // chunk classes: 0 = W (row stride 512 f32), 1 = D (expert stride TOT_N), 2 = A
    const char* gsrc[6];
    int loff[6];
    int cls[6];
    #pragma unroll
    for (int i = 0; i < 6; ++i) {
        const int q = w * 6 + i;
        if (q < 8) {
            const int off = q * 1024 + l * 16;
            const int row = off >> 8;
            const int kb  = (off & 255) ^ (((off >> 8) & 7) << 4);
            gsrc[i] = (const char*)(W + (size_t)(nt * 32 + row) * R_N) + kb;
            loff[i] = q * 1024;
            cls[i] = 0;
        } else if (q < 16) {
            const int c = q - 8;
            const int off = c * 1024 + l * 16;
            const int row = off >> 8;
            const int kb  = (off & 255) ^ (((off >> 8) & 7) << 4);
            gsrc[i] = (const char*)(D + (size_t)(nt * 32 + row) * R_N) + kb;
            loff[i] = 8192 + c * 1024;
            cls[i] = 1;
        } else {
            const int c = q - 16;
            const int off = c * 1024 + l * 16;
            const int row = off >> 7;
            const int kb  = (off & 127) ^ (((off >> 7) & 7) << 4);
            gsrc[i] = (const char*)(A + (size_t)row * KT) + kb;
            loff[i] = 16384 + c * 1024;
            cls[i] = 2;
        }
    }

    f32x4 acc[2] = {};
    const int wrow = wn * 16 + lr;
    const int wswz = (wrow & 7) << 4;
    const int arow0 = wm * 32 + lr;
    const int aswz = (arow0 & 7) << 4;

    // per-tile source offset (piecewise-affine in kk for D; e = kk>>9)
    auto toff = [](int c, int kk) -> size_t {
        if (c == 0) return (size_t)(kk & 511) * 4;
        if (c == 1) return ((size_t)(kk >> 9) * (size_t)TOT_N + (kk & 511)) * 4;
        return (size_t)kk * 2;
    };

    #pragma unroll
    for (int i = 0; i < 6; ++i)
        stage16(gsrc[i] + toff(cls[i], 0), smem + loff[i]);
    __syncthreads();

    for (int t = 0; t < NTILES; ++t) {
        if (t + 1 < NTILES) {
            const int kk = (t + 1) * 64;
            char* b = smem + ((t + 1) & 1) * BUFSZ;
            #pragma unroll
            for (int i = 0; i < 6; ++i)
                stage16(gsrc[i] + toff(cls[i], kk), b + loff[i]);
        }

        const char* buf = smem + (t & 1) * BUFSZ;
        #pragma unroll
        for (int inner = 0; inner < 2; ++inner) {
            const int b0 = (inner * 32 + lk) * 4;
            const char* wrp = buf + wrow * 256;
            const char* drp = buf + 8192 + wrow * 256;
            f32x4 w0 = *(const f32x4*)(wrp + ((b0)      ^ wswz));
            f32x4 w1 = *(const f32x4*)(wrp + ((b0 + 16) ^ wswz));
            f32x4 d0 = *(const f32x4*)(drp + ((b0)      ^ wswz));
            f32x4 d1 = *(const f32x4*)(drp + ((b0 + 16) ^ wswz));
            f32x4 s0 = w0 + d0;
            f32x4 s1 = w1 + d1;
            bf16x8 bhi, blo;
            #pragma unroll
            for (int j = 0; j < 4; ++j) {
                unsigned short h0 = f2bf_bits(s0[j]);
                bhi[j] = (short)h0;
                blo[j] = (short)f2bf_bits(s0[j] - bfbits2f(h0));
                unsigned short h1 = f2bf_bits(s1[j]);
                bhi[j + 4] = (short)h1;
                blo[j + 4] = (short)f2bf_bits(s1[j] - bfbits2f(h1));
            }
            const int ab = (inner * 32 + lk) * 2;
            #pragma unroll
            for (int mf = 0; mf < 2; ++mf) {
                const int ar = arow0 + mf * 16;
                const char* arp = buf + 16384 + ar * 128;
                bf16x8 af = *(const bf16x8*)(arp + (ab ^ aswz));
                acc[mf] = __builtin_amdgcn_mfma_f32_16x16x32_bf16(af, bhi, acc[mf], 0, 0, 0);
                acc[mf] = __builtin_amdgcn_mfma_f32_16x16x32_bf16(af, blo, acc[mf], 0, 0, 0);
            }
        }
        __syncthreads();
    }

    const int rb = (l >> 4) * 4;
    const int nrow = nt * 32 + wrow;
    #pragma unroll
    for (int j = 0; j < 2; ++j) {
        #pragma unroll
        for (int i = 0; i < 4; ++i) {
            const int row = wm * 32 + j * 16 + rb + i;
            Out[(size_t)row * OUT_N + nrow] = acc[j][i];
        }
    }
}

// h1b[e,b,r] = bf16( sum_ks P[e,ks,b,r] )
template<int KS, int BN>
__global__ __launch_bounds__(256)
void reduce_ks_bf16(const float* __restrict__ P, __hip_bfloat16* __restrict__ H)
{
    const int gt = blockIdx.x * 256 + threadIdx.x;
    const int e = gt / BN;
    const int r = gt - e * BN;
    const float* base = P + (size_t)e * KS * BN + r;
    float s = 0.0f;
    #pragma unroll
    for (int k = 0; k < KS; ++k) s += base[(size_t)k * BN];
    H[gt] = __float2bfloat16(s);
}

// h3s[b, e*512+r] = scores[e] * bf16( sum_ks P[e,ks,b,r] )   (scores folded, transposed)
__global__ __launch_bounds__(256)
void reduce_ks_scaled(const float* __restrict__ P, const float* __restrict__ scores,
                      __hip_bfloat16* __restrict__ H)
{
    const int gt = blockIdx.x * 256 + threadIdx.x;   // 0 .. E*B*R-1
    const int e = gt >> 15;                          // B*R = 32768
    const int rem = gt & 32767;
    const int b = rem >> 9;
    const int r = rem & 511;
    const float* base = P + (size_t)e * 8 * 32768 + rem;
    float s = 0.0f;
    #pragma unroll
    for (int k = 0; k < 8; ++k) s += base[(size_t)k * 32768];
    const float v = scores[e] * __bfloat162float(__float2bfloat16(s));
    H[(size_t)b * (E_N * R_N) + e * R_N + r] = __float2bfloat16(v);
}

__global__ __launch_bounds__(256)
void convert_bf16(const float* __restrict__ X, __hip_bfloat16* __restrict__ Xb)
{
    const int gt = blockIdx.x * 256 + threadIdx.x;
    const int idx = gt * 2;
    const float2 v = *(const float2*)(X + idx);
    const unsigned u = ((unsigned)f2bf_bits(v.y) << 16) | f2bf_bits(v.x);
    *(unsigned*)((char*)Xb + (size_t)idx * 2) = u;
}

extern "C" void kernel_launch(void* const* d_in, const int* in_sizes, int n_in,
                              void* d_out, int out_size, void* d_ws, size_t ws_size,
                              hipStream_t stream)
{
    const float* x      = (const float*)d_in[0];
    const float* scores = (const float*)d_in[1];
    const float* delta  = (const float*)d_in[2];
    const float* W1     = (const float*)d_in[3];
    const float* W2     = (const float*)d_in[4];
    const float* W3     = (const float*)d_in[5];
    const float* W4     = (const float*)d_in[6];
    float* out = (float*)d_out;

    char* ws = (char*)d_ws;
    __hip_bfloat16* xb  = (__hip_bfloat16*)(ws);                    // 512 KB
    __hip_bfloat16* h1b = (__hip_bfloat16*)(ws + 524288);           // 256 KB
    __hip_bfloat16* h2b = (__hip_bfloat16*)(ws + 786432);           // 2 MB
    __hip_bfloat16* h3s = (__hip_bfloat16*)(ws + 2883584);          // 256 KB [64][2048]
    float* P1 = (float*)(ws + 3145728);                             // 4 MB
    float* P3 = (float*)(ws + 7340032);                             // 4 MB

    const float* d1 = delta;
    const float* d2 = d1 + (size_t)R_N * IN_N;
    const float* d3 = d2 + (size_t)H_N * R_N;
    const float* d4 = d3 + (size_t)R_N * H_N;

    convert_bf16<<<dim3(B_N * IN_N / 2 / 256), dim3(256), 0, stream>>>(x, xb);

    // L1: K=4096, N=512, KS=8
    gemm_layer<IN_N, R_N, 8, true, false, false>
        <<<dim3(E_N * (R_N / 32) * 8), dim3(256), 0, stream>>>(xb, W1, d1, P1, nullptr);
    reduce_ks_bf16<8, B_N * R_N>
        <<<dim3(E_N * B_N * R_N / 256), dim3(256), 0, stream>>>(P1, h1b);

    // L2: K=512, N=4096, relu -> bf16
    gemm_layer<R_N, H_N, 1, false, true, true>
        <<<dim3(E_N * (H_N / 32)), dim3(256), 0, stream>>>(h1b, W2, d2, nullptr, h2b);

    // L3: K=4096, N=512, KS=8
    gemm_layer<H_N, R_N, 8, false, false, false>
        <<<dim3(E_N * (R_N / 32) * 8), dim3(256), 0, stream>>>(h2b, W3, d3, P3, nullptr);
    // h3s = scores-scaled, [b, e*512+r] transposed
    reduce_ks_scaled<<<dim3(E_N * B_N * R_N / 256), dim3(256), 0, stream>>>(P3, scores, h3s);

    // L4: single GEMM K=2048 (e folded into K), writes f32 out directly
    gemm_l4<<<dim3(OUT_N / 32), dim3(256), 0, stream>>>(h3s, W4, d4, out);
}

// Round 11
// 54.257 us; speedup vs baseline: 3.8187x; 1.1762x over previous
//
#include <hip/hip_runtime.h>
#include <hip/hip_bf16.h>

#define E_N 4
#define B_N 64
#define IN_N 4096
#define H_N 4096
#define R_N 512
#define OUT_N 4096
#define TOT_N 8388608  // R*IN + H*R + R*H + OUT*R

typedef float f32x4 __attribute__((ext_vector_type(4)));
typedef short bf16x8 __attribute__((ext_vector_type(8)));

__device__ __forceinline__ unsigned short f2bf_bits(float f) {
    return __builtin_bit_cast(unsigned short, __float2bfloat16(f));
}
__device__ __forceinline__ float bfbits2f(unsigned short u) {
    return __builtin_bit_cast(float, ((unsigned)u) << 16);
}

__device__ __forceinline__ void stage16(const void* g, void* l) {
    __builtin_amdgcn_global_load_lds(
        (const __attribute__((address_space(1))) void*)g,
        (__attribute__((address_space(3))) void*)l, 16, 0, 0);
}

// ---------------- R6 gemm (layers 1-3): best verified body, unchanged ----------------
// C[e,b,n] = sum_k A[e?,b,k] * (W[n,k] + D[e,n,k])
template<int K_TOT, int N_TOT, int KS, bool A_SHARED, bool RELU, bool OUT_BF16>
__global__ __launch_bounds__(256, 2)
void gemm_layer(const __hip_bfloat16* __restrict__ A, const float* __restrict__ W,
                const float* __restrict__ D, float* __restrict__ OutF,
                __hip_bfloat16* __restrict__ OutB)
{
    constexpr int KCH = K_TOT / KS;
    constexpr int NT = N_TOT / 32;
    constexpr int NTILES = KCH / 64;
    constexpr int BUFSZ = 24576;
    __shared__ __align__(16) char smem[2 * BUFSZ];

    const int bid = blockIdx.x;
    const int ks = bid % KS;
    const int nt = (bid / KS) % NT;
    const int e  = bid / (KS * NT);
    const int tid = threadIdx.x;
    const int l  = tid & 63;
    const int w  = tid >> 6;
    const int wn = w & 1;
    const int wm = w >> 1;
    const int lr = l & 15;
    const int lk = (l >> 4) << 3;

    const float* Wb = W + (size_t)(nt * 32) * K_TOT + ks * KCH;
    const float* Db = D + (size_t)e * TOT_N + (size_t)(nt * 32) * K_TOT + ks * KCH;
    const __hip_bfloat16* Ab = A + (A_SHARED ? (size_t)0 : (size_t)e * B_N * K_TOT)
                                 + ks * KCH;

    const char* gsrc[6];
    int loff[6];
    int kstep[6];
    #pragma unroll
    for (int i = 0; i < 6; ++i) {
        const int q = w * 6 + i;
        if (q < 8) {
            const int off = q * 1024 + l * 16;
            const int row = off >> 8;
            const int kb  = off & 255;
            gsrc[i] = (const char*)(Wb + (size_t)row * K_TOT) + (kb ^ ((row & 7) << 4));
            loff[i] = q * 1024;
            kstep[i] = 4;
        } else if (q < 16) {
            const int c = q - 8;
            const int off = c * 1024 + l * 16;
            const int row = off >> 8;
            const int kb  = off & 255;
            gsrc[i] = (const char*)(Db + (size_t)row * K_TOT) + (kb ^ ((row & 7) << 4));
            loff[i] = 8192 + c * 1024;
            kstep[i] = 4;
        } else {
            const int c = q - 16;
            const int off = c * 1024 + l * 16;
            const int row = off >> 7;
            const int kb  = off & 127;
            gsrc[i] = (const char*)(Ab + (size_t)row * K_TOT) + (kb ^ ((row & 7) << 4));
            loff[i] = 16384 + c * 1024;
            kstep[i] = 2;
        }
    }

    f32x4 acc[2] = {};
    const int wrow = wn * 16 + lr;
    const int wswz = (wrow & 7) << 4;
    const int arow0 = wm * 32 + lr;
    const int aswz = (arow0 & 7) << 4;

    #pragma unroll
    for (int i = 0; i < 6; ++i)
        stage16(gsrc[i], smem + loff[i]);
    __syncthreads();

    for (int t = 0; t < NTILES; ++t) {
        if (t + 1 < NTILES) {
            const int kk = (t + 1) * 64;
            char* b = smem + ((t + 1) & 1) * BUFSZ;
            #pragma unroll
            for (int i = 0; i < 6; ++i)
                stage16(gsrc[i] + kk * kstep[i], b + loff[i]);
        }

        const char* buf = smem + (t & 1) * BUFSZ;
        #pragma unroll
        for (int inner = 0; inner < 2; ++inner) {
            const int b0 = (inner * 32 + lk) * 4;
            const char* wrp = buf + wrow * 256;
            const char* drp = buf + 8192 + wrow * 256;
            f32x4 w0 = *(const f32x4*)(wrp + ((b0)      ^ wswz));
            f32x4 w1 = *(const f32x4*)(wrp + ((b0 + 16) ^ wswz));
            f32x4 d0 = *(const f32x4*)(drp + ((b0)      ^ wswz));
            f32x4 d1 = *(const f32x4*)(drp + ((b0 + 16) ^ wswz));
            f32x4 s0 = w0 + d0;
            f32x4 s1 = w1 + d1;
            bf16x8 bhi, blo;
            #pragma unroll
            for (int j = 0; j < 4; ++j) {
                unsigned short h0 = f2bf_bits(s0[j]);
                bhi[j] = (short)h0;
                blo[j] = (short)f2bf_bits(s0[j] - bfbits2f(h0));
                unsigned short h1 = f2bf_bits(s1[j]);
                bhi[j + 4] = (short)h1;
                blo[j + 4] = (short)f2bf_bits(s1[j] - bfbits2f(h1));
            }
            const int ab = (inner * 32 + lk) * 2;
            #pragma unroll
            for (int mf = 0; mf < 2; ++mf) {
                const int ar = arow0 + mf * 16;
                const char* arp = buf + 16384 + ar * 128;
                bf16x8 af = *(const bf16x8*)(arp + (ab ^ aswz));
                acc[mf] = __builtin_amdgcn_mfma_f32_16x16x32_bf16(af, bhi, acc[mf], 0, 0, 0);
                acc[mf] = __builtin_amdgcn_mfma_f32_16x16x32_bf16(af, blo, acc[mf], 0, 0, 0);
            }
        }
        __syncthreads();
    }

    const int rb = (l >> 4) * 4;
    const int nrow = nt * 32 + wrow;
    #pragma unroll
    for (int j = 0; j < 2; ++j) {
        #pragma unroll
        for (int i = 0; i < 4; ++i) {
            const int row = wm * 32 + j * 16 + rb + i;
            float v = acc[j][i];
            if (RELU) v = fmaxf(v, 0.0f);
            if (OUT_BF16) {
                OutB[(size_t)e * B_N * N_TOT + (size_t)row * N_TOT + nrow] =
                    __float2bfloat16(v);
            } else {
                OutF[(size_t)(e * KS + ks) * B_N * N_TOT + (size_t)row * N_TOT + nrow] = v;
            }
        }
    }
}

// ---------------- L4: e-as-K fused expert combine, split-K=4 ----------------
// Block (ks 0..3, nt 0..127); K-chunk ks covers k in [ks*512,(ks+1)*512) ==
// exactly expert ks.  P[ks][b][o] partial, f32.  512 blocks.
__global__ __launch_bounds__(256, 2)
void gemm_l4s(const __hip_bfloat16* __restrict__ A, const float* __restrict__ W,
              const float* __restrict__ D, float* __restrict__ P)
{
    constexpr int KT = E_N * R_N;        // 2048 (A row stride)
    constexpr int NTILES = 8;            // 512 / 64
    constexpr int BUFSZ = 24576;
    __shared__ __align__(16) char smem[2 * BUFSZ];

    const int bid = blockIdx.x;
    const int ks = bid & 3;              // expert / K-chunk
    const int nt = bid >> 2;             // 0..127
    const int tid = threadIdx.x;
    const int l  = tid & 63;
    const int w  = tid >> 6;
    const int wn = w & 1;
    const int wm = w >> 1;
    const int lr = l & 15;
    const int lk = (l >> 4) << 3;

    const float* Wb = W + (size_t)(nt * 32) * R_N;
    const float* Db = D + (size_t)ks * TOT_N + (size_t)(nt * 32) * R_N;
    const __hip_bfloat16* Ab = A + ks * R_N;   // + row*KT per row

    const char* gsrc[6];
    int loff[6];
    int kstep[6];
    #pragma unroll
    for (int i = 0; i < 6; ++i) {
        const int q = w * 6 + i;
        if (q < 8) {
            const int off = q * 1024 + l * 16;
            const int row = off >> 8;
            const int kb  = (off & 255) ^ ((row & 7) << 4);
            gsrc[i] = (const char*)(Wb + (size_t)row * R_N) + kb;
            loff[i] = q * 1024;
            kstep[i] = 4;
        } else if (q < 16) {
            const int c = q - 8;
            const int off = c * 1024 + l * 16;
            const int row = off >> 8;
            const int kb  = (off & 255) ^ ((row & 7) << 4);
            gsrc[i] = (const char*)(Db + (size_t)row * R_N) + kb;
            loff[i] = 8192 + c * 1024;
            kstep[i] = 4;
        } else {
            const int c = q - 16;
            const int off = c * 1024 + l * 16;
            const int row = off >> 7;
            const int kb  = (off & 127) ^ ((row & 7) << 4);
            gsrc[i] = (const char*)(Ab + (size_t)row * KT) + kb;
            loff[i] = 16384 + c * 1024;
            kstep[i] = 2;
        }
    }

    f32x4 acc[2] = {};
    const int wrow = wn * 16 + lr;
    const int wswz = (wrow & 7) << 4;
    const int arow0 = wm * 32 + lr;
    const int aswz = (arow0 & 7) << 4;

    #pragma unroll
    for (int i = 0; i < 6; ++i)
        stage16(gsrc[i], smem + loff[i]);
    __syncthreads();

    for (int t = 0; t < NTILES; ++t) {
        if (t + 1 < NTILES) {
            const int kk = (t + 1) * 64;
            char* b = smem + ((t + 1) & 1) * BUFSZ;
            #pragma unroll
            for (int i = 0; i < 6; ++i)
                stage16(gsrc[i] + kk * kstep[i], b + loff[i]);
        }

        const char* buf = smem + (t & 1) * BUFSZ;
        #pragma unroll
        for (int inner = 0; inner < 2; ++inner) {
            const int b0 = (inner * 32 + lk) * 4;
            const char* wrp = buf + wrow * 256;
            const char* drp = buf + 8192 + wrow * 256;
            f32x4 w0 = *(const f32x4*)(wrp + ((b0)      ^ wswz));
            f32x4 w1 = *(const f32x4*)(wrp + ((b0 + 16) ^ wswz));
            f32x4 d0 = *(const f32x4*)(drp + ((b0)      ^ wswz));
            f32x4 d1 = *(const f32x4*)(drp + ((b0 + 16) ^ wswz));
            f32x4 s0 = w0 + d0;
            f32x4 s1 = w1 + d1;
            bf16x8 bhi, blo;
            #pragma unroll
            for (int j = 0; j < 4; ++j) {
                unsigned short h0 = f2bf_bits(s0[j]);
                bhi[j] = (short)h0;
                blo[j] = (short)f2bf_bits(s0[j] - bfbits2f(h0));
                unsigned short h1 = f2bf_bits(s1[j]);
                bhi[j + 4] = (short)h1;
                blo[j + 4] = (short)f2bf_bits(s1[j] - bfbits2f(h1));
            }
            const int ab = (inner * 32 + lk) * 2;
            #pragma unroll
            for (int mf = 0; mf < 2; ++mf) {
                const int ar = arow0 + mf * 16;
                const char* arp = buf + 16384 + ar * 128;
                bf16x8 af = *(const bf16x8*)(arp + (ab ^ aswz));
                acc[mf] = __builtin_amdgcn_mfma_f32_16x16x32_bf16(af, bhi, acc[mf], 0, 0, 0);
                acc[mf] = __builtin_amdgcn_mfma_f32_16x16x32_bf16(af, blo, acc[mf], 0, 0, 0);
            }
        }
        __syncthreads();
    }

    const int rb = (l >> 4) * 4;
    const int nrow = nt * 32 + wrow;
    #pragma unroll
    for (int j = 0; j < 2; ++j) {
        #pragma unroll
        for (int i = 0; i < 4; ++i) {
            const int row = wm * 32 + j * 16 + rb + i;
            P[(size_t)(ks * B_N + row) * OUT_N + nrow] = acc[j][i];
        }
    }
}

// out[b,o] = sum_ks P[ks][b][o], ks ascending (deterministic)
__global__ __launch_bounds__(256)
void reduce4(const float* __restrict__ P, float* __restrict__ out)
{
    const int gt = blockIdx.x * 256 + threadIdx.x;
    const int idx = gt * 4;
    f32x4 s = {};
    #pragma unroll
    for (int k = 0; k < 4; ++k)
        s += *(const f32x4*)(P + (size_t)k * (B_N * OUT_N) + idx);
    *(f32x4*)(out + idx) = s;
}

// h1b[e,b,r] = bf16( sum_ks P[e,ks,b,r] )
template<int KS, int BN>
__global__ __launch_bounds__(256)
void reduce_ks_bf16(const float* __restrict__ P, __hip_bfloat16* __restrict__ H)
{
    const int gt = blockIdx.x * 256 + threadIdx.x;
    const int e = gt / BN;
    const int r = gt - e * BN;
    const float* base = P + (size_t)e * KS * BN + r;
    float s = 0.0f;
    #pragma unroll
    for (int k = 0; k < KS; ++k) s += base[(size_t)k * BN];
    H[gt] = __float2bfloat16(s);
}

// h3s[b, e*512+r] = scores[e] * bf16( sum_ks P[e,ks,b,r] )
__global__ __launch_bounds__(256)
void reduce_ks_scaled(const float* __restrict__ P, const float* __restrict__ scores,
                      __hip_bfloat16* __restrict__ H)
{
    const int gt = blockIdx.x * 256 + threadIdx.x;   // 0 .. E*B*R-1
    const int e = gt >> 15;                          // B*R = 32768
    const int rem = gt & 32767;
    const int b = rem >> 9;
    const int r = rem & 511;
    const float* base = P + (size_t)e * 8 * 32768 + rem;
    float s = 0.0f;
    #pragma unroll
    for (int k = 0; k < 8; ++k) s += base[(size_t)k * 32768];
    const float v = scores[e] * __bfloat162float(__float2bfloat16(s));
    H[(size_t)b * (E_N * R_N) + e * R_N + r] = __float2bfloat16(v);
}

__global__ __launch_bounds__(256)
void convert_bf16(const float* __restrict__ X, __hip_bfloat16* __restrict__ Xb)
{
    const int gt = blockIdx.x * 256 + threadIdx.x;
    const int idx = gt * 2;
    const float2 v = *(const float2*)(X + idx);
    const unsigned u = ((unsigned)f2bf_bits(v.y) << 16) | f2bf_bits(v.x);
    *(unsigned*)((char*)Xb + (size_t)idx * 2) = u;
}

extern "C" void kernel_launch(void* const* d_in, const int* in_sizes, int n_in,
                              void* d_out, int out_size, void* d_ws, size_t ws_size,
                              hipStream_t stream)
{
    const float* x      = (const float*)d_in[0];
    const float* scores = (const float*)d_in[1];
    const float* delta  = (const float*)d_in[2];
    const float* W1     = (const float*)d_in[3];
    const float* W2     = (const float*)d_in[4];
    const float* W3     = (const float*)d_in[5];
    const float* W4     = (const float*)d_in[6];
    float* out = (float*)d_out;

    char* ws = (char*)d_ws;
    __hip_bfloat16* xb  = (__hip_bfloat16*)(ws);                    // 512 KB
    __hip_bfloat16* h1b = (__hip_bfloat16*)(ws + 524288);           // 256 KB
    __hip_bfloat16* h2b = (__hip_bfloat16*)(ws + 786432);           // 2 MB
    __hip_bfloat16* h3s = (__hip_bfloat16*)(ws + 2883584);          // 256 KB [64][2048]
    float* P1 = (float*)(ws + 3145728);                             // 4 MB
    float* P3 = (float*)(ws + 7340032);                             // 4 MB
    float* P4 = (float*)(ws + 11534336);                            // 4 MB [4][64][4096]

    const float* d1 = delta;
    const float* d2 = d1 + (size_t)R_N * IN_N;
    const float* d3 = d2 + (size_t)H_N * R_N;
    const float* d4 = d3 + (size_t)R_N * H_N;

    convert_bf16<<<dim3(B_N * IN_N / 2 / 256), dim3(256), 0, stream>>>(x, xb);

    // L1: K=4096, N=512, KS=8
    gemm_layer<IN_N, R_N, 8, true, false, false>
        <<<dim3(E_N * (R_N / 32) * 8), dim3(256), 0, stream>>>(xb, W1, d1, P1, nullptr);
    reduce_ks_bf16<8, B_N * R_N>
        <<<dim3(E_N * B_N * R_N / 256), dim3(256), 0, stream>>>(P1, h1b);

    // L2: K=512, N=4096, relu -> bf16
    gemm_layer<R_N, H_N, 1, false, true, true>
        <<<dim3(E_N * (H_N / 32)), dim3(256), 0, stream>>>(h1b, W2, d2, nullptr, h2b);

    // L3: K=4096, N=512, KS=8
    gemm_layer<H_N, R_N, 8, false, false, false>
        <<<dim3(E_N * (R_N / 32) * 8), dim3(256), 0, stream>>>(h2b, W3, d3, P3, nullptr);
    // h3s = scores-scaled, [b, e*512+r]
    reduce_ks_scaled<<<dim3(E_N * B_N * R_N / 256), dim3(256), 0, stream>>>(P3, scores, h3s);

    // L4: e-as-K, split-K=4 (one expert per chunk), 512 blocks -> partials
    gemm_l4s<<<dim3(4 * (OUT_N / 32)), dim3(256), 0, stream>>>(h3s, W4, d4, P4);
    // out = sum_ks P4[ks]
    reduce4<<<dim3(B_N * OUT_N / 4 / 256), dim3(256), 0, stream>>>(P4, out);
}

// Round 12
// 48.474 us; speedup vs baseline: 4.2742x; 1.1193x over previous
//
#include <hip/hip_runtime.h>
#include <hip/hip_bf16.h>

#define E_N 4
#define B_N 64
#define IN_N 4096
#define H_N 4096
#define R_N 512
#define OUT_N 4096
#define TOT_N 8388608  // R*IN + H*R + R*H + OUT*R

typedef float f32x4 __attribute__((ext_vector_type(4)));
typedef short bf16x8 __attribute__((ext_vector_type(8)));
typedef unsigned short u16x8 __attribute__((ext_vector_type(8)));

__device__ __forceinline__ unsigned short f2bf_bits(float f) {
    return __builtin_bit_cast(unsigned short, __float2bfloat16(f));
}
__device__ __forceinline__ float bfbits2f(unsigned short u) {
    return __builtin_bit_cast(float, ((unsigned)u) << 16);
}

__device__ __forceinline__ void stage16(const void* g, void* l) {
    __builtin_amdgcn_global_load_lds(
        (const __attribute__((address_space(1))) void*)g,
        (__attribute__((address_space(3))) void*)l, 16, 0, 0);
}

// C[e,b,n] = sum_k A[e?,b,k] * (W[n,k] + D[e,n,k])
// R6 body (best verified: 51.4 us) + CONV_A: when true, A is f32 and the A
// chunks are reg-staged (global f32 load -> cvt bf16 -> swizzled ds_write_b128),
// fusing the x->bf16 conversion into L1 and removing one dispatch boundary.
// Chunk->wave map q = w + 4i gives every wave 2 A chunks (balanced).
template<int K_TOT, int N_TOT, int KS, bool A_SHARED, bool RELU, bool OUT_BF16,
         bool CONV_A>
__global__ __launch_bounds__(256, 2)
void gemm_layer(const __hip_bfloat16* __restrict__ A, const float* __restrict__ AF,
                const float* __restrict__ W, const float* __restrict__ D,
                float* __restrict__ OutF, __hip_bfloat16* __restrict__ OutB)
{
    constexpr int KCH = K_TOT / KS;      // 512 for every layer
    constexpr int NT = N_TOT / 32;
    constexpr int NTILES = KCH / 64;     // 8
    constexpr int BUFSZ = 24576;
    __shared__ __align__(16) char smem[2 * BUFSZ];  // [buf][ Wt 8K | Dt 8K | At 8K ]

    const int bid = blockIdx.x;
    const int ks = bid % KS;
    const int nt = (bid / KS) % NT;
    const int e  = bid / (KS * NT);
    const int tid = threadIdx.x;
    const int l  = tid & 63;
    const int w  = tid >> 6;
    const int wn = w & 1;
    const int wm = w >> 1;
    const int lr = l & 15;
    const int lk = (l >> 4) << 3;

    const float* Wb = W + (size_t)(nt * 32) * K_TOT + ks * KCH;
    const float* Db = D + (size_t)e * TOT_N + (size_t)(nt * 32) * K_TOT + ks * KCH;
    const __hip_bfloat16* Ab = A + (A_SHARED ? (size_t)0 : (size_t)e * B_N * K_TOT)
                                 + ks * KCH;
    const float* AFb = AF ? (AF + (A_SHARED ? (size_t)0 : (size_t)e * B_N * K_TOT)
                                + ks * KCH)
                          : nullptr;

    // 24 1-KB chunks: q 0-7 Wt, 8-15 Dt, 16-23 At.  q = w + 4*i  (i>=4 <=> A chunk)
    const char* gsrc[6];
    int loff[6];     // wave-uniform LDS offset (stage16 chunks)
    int lws[6];      // per-lane swizzled LDS byte (CONV_A A chunks)
    int kstep[6];
    #pragma unroll
    for (int i = 0; i < 6; ++i) {
        const int q = w + i * 4;
        if (q < 8) {
            const int off = q * 1024 + l * 16;
            const int row = off >> 8;
            const int kb  = off & 255;
            gsrc[i] = (const char*)(Wb + (size_t)row * K_TOT) + (kb ^ ((row & 7) << 4));
            loff[i] = q * 1024;
            kstep[i] = 4;
        } else if (q < 16) {
            const int c = q - 8;
            const int off = c * 1024 + l * 16;
            const int row = off >> 8;
            const int kb  = off & 255;
            gsrc[i] = (const char*)(Db + (size_t)row * K_TOT) + (kb ^ ((row & 7) << 4));
            loff[i] = 8192 + c * 1024;
            kstep[i] = 4;
        } else {
            const int c = q - 16;
            const int off = c * 1024 + l * 16;
            const int row = off >> 7;            // 128 B per bf16 row of 64
            const int kb  = off & 127;
            if (CONV_A) {
                // linear f32 source; swizzle applied on the LDS write side
                gsrc[i] = (const char*)(AFb + (size_t)row * K_TOT) + kb * 2;
                lws[i]  = 16384 + (off & ~127) + (kb ^ ((row & 7) << 4));
                kstep[i] = 4;
            } else {
                gsrc[i] = (const char*)(Ab + (size_t)row * K_TOT) + (kb ^ ((row & 7) << 4));
                loff[i] = 16384 + c * 1024;
                kstep[i] = 2;
            }
        }
    }

    auto stage_all = [&](int kk, char* b) {
        #pragma unroll
        for (int i = 0; i < 6; ++i) {
            if (CONV_A && i >= 4) {
                const char* src = gsrc[i] + (size_t)kk * 4;
                f32x4 a0 = *(const f32x4*)(src);
                f32x4 a1 = *(const f32x4*)(src + 16);
                u16x8 o;
                #pragma unroll
                for (int j = 0; j < 4; ++j) {
                    o[j]     = f2bf_bits(a0[j]);
                    o[j + 4] = f2bf_bits(a1[j]);
                }
                *(u16x8*)(b + lws[i]) = o;
            } else {
                stage16(gsrc[i] + (size_t)kk * kstep[i], b + loff[i]);
            }
        }
    };

    f32x4 acc[2] = {};
    const int wrow = wn * 16 + lr;
    const int wswz = (wrow & 7) << 4;
    const int arow0 = wm * 32 + lr;
    const int aswz = (arow0 & 7) << 4;

    stage_all(0, smem);
    __syncthreads();

    for (int t = 0; t < NTILES; ++t) {
        if (t + 1 < NTILES)
            stage_all((t + 1) * 64, smem + ((t + 1) & 1) * BUFSZ);

        const char* buf = smem + (t & 1) * BUFSZ;
        #pragma unroll
        for (int inner = 0; inner < 2; ++inner) {
            const int b0 = (inner * 32 + lk) * 4;
            const char* wrp = buf + wrow * 256;
            const char* drp = buf + 8192 + wrow * 256;
            f32x4 w0 = *(const f32x4*)(wrp + ((b0)      ^ wswz));
            f32x4 w1 = *(const f32x4*)(wrp + ((b0 + 16) ^ wswz));
            f32x4 d0 = *(const f32x4*)(drp + ((b0)      ^ wswz));
            f32x4 d1 = *(const f32x4*)(drp + ((b0 + 16) ^ wswz));
            f32x4 s0 = w0 + d0;
            f32x4 s1 = w1 + d1;
            bf16x8 bhi, blo;
            #pragma unroll
            for (int j = 0; j < 4; ++j) {
                unsigned short h0 = f2bf_bits(s0[j]);
                bhi[j] = (short)h0;
                blo[j] = (short)f2bf_bits(s0[j] - bfbits2f(h0));
                unsigned short h1 = f2bf_bits(s1[j]);
                bhi[j + 4] = (short)h1;
                blo[j + 4] = (short)f2bf_bits(s1[j] - bfbits2f(h1));
            }
            const int ab = (inner * 32 + lk) * 2;
            #pragma unroll
            for (int mf = 0; mf < 2; ++mf) {
                const int ar = arow0 + mf * 16;
                const char* arp = buf + 16384 + ar * 128;
                bf16x8 af = *(const bf16x8*)(arp + (ab ^ aswz));
                acc[mf] = __builtin_amdgcn_mfma_f32_16x16x32_bf16(af, bhi, acc[mf], 0, 0, 0);
                acc[mf] = __builtin_amdgcn_mfma_f32_16x16x32_bf16(af, blo, acc[mf], 0, 0, 0);
            }
        }
        __syncthreads();
    }

    // C/D layout: col = l&15 (== nrow), row(frag) = (l>>4)*4 + i
    const int rb = (l >> 4) * 4;
    const int nrow = nt * 32 + wrow;
    #pragma unroll
    for (int j = 0; j < 2; ++j) {
        #pragma unroll
        for (int i = 0; i < 4; ++i) {
            const int row = wm * 32 + j * 16 + rb + i;
            float v = acc[j][i];
            if (RELU) v = fmaxf(v, 0.0f);
            if (OUT_BF16) {
                OutB[(size_t)e * B_N * N_TOT + (size_t)row * N_TOT + nrow] =
                    __float2bfloat16(v);
            } else {
                OutF[(size_t)(e * KS + ks) * B_N * N_TOT + (size_t)row * N_TOT + nrow] = v;
            }
        }
    }
}

// h1b[e,b,r] = bf16( sum_ks P[e,ks,b,r] )  — 1 output/thread (R6-verified)
template<int KS, int BN>
__global__ __launch_bounds__(256)
void reduce_ks_bf16(const float* __restrict__ P, __hip_bfloat16* __restrict__ H)
{
    const int gt = blockIdx.x * 256 + threadIdx.x;
    const int e = gt / BN;
    const int r = gt - e * BN;
    const float* base = P + (size_t)e * KS * BN + r;
    float s = 0.0f;
    #pragma unroll
    for (int k = 0; k < KS; ++k) s += base[(size_t)k * BN];
    H[gt] = __float2bfloat16(s);
}

// out[b,o] = sum_e scores[e] * P[e,b,o]  (R6-verified)
__global__ __launch_bounds__(256)
void reduce_experts(const float* __restrict__ P, const float* __restrict__ scores,
                    float* __restrict__ out)
{
    const int gt = blockIdx.x * 256 + threadIdx.x;
    const int idx = gt * 2;
    float2 acc = {0.0f, 0.0f};
    #pragma unroll
    for (int e = 0; e < E_N; ++e) {
        const float2 v = *(const float2*)(P + (size_t)e * (B_N * OUT_N) + idx);
        const float s = scores[e];
        acc.x += s * v.x;
        acc.y += s * v.y;
    }
    *(float2*)(out + idx) = acc;
}

extern "C" void kernel_launch(void* const* d_in, const int* in_sizes, int n_in,
                              void* d_out, int out_size, void* d_ws, size_t ws_size,
                              hipStream_t stream)
{
    const float* x      = (const float*)d_in[0];
    const float* scores = (const float*)d_in[1];
    const float* delta  = (const float*)d_in[2];
    const float* W1     = (const float*)d_in[3];
    const float* W2     = (const float*)d_in[4];
    const float* W3     = (const float*)d_in[5];
    const float* W4     = (const float*)d_in[6];
    float* out = (float*)d_out;

    char* ws = (char*)d_ws;
    __hip_bfloat16* h1b = (__hip_bfloat16*)(ws + 524288);           // 256 KB
    __hip_bfloat16* h2b = (__hip_bfloat16*)(ws + 786432);           // 2 MB
    __hip_bfloat16* h3b = (__hip_bfloat16*)(ws + 2883584);          // 256 KB
    float* P1 = (float*)(ws + 3145728);                             // 4 MB
    float* P3 = (float*)(ws + 7340032);                             // 4 MB
    float* P4 = (float*)(ws + 11534336);                            // 4 MB

    const float* d1 = delta;
    const float* d2 = d1 + (size_t)R_N * IN_N;
    const float* d3 = d2 + (size_t)H_N * R_N;
    const float* d4 = d3 + (size_t)R_N * H_N;

    // L1: K=4096, N=512, KS=8 — x (f32) converted in-kernel (CONV_A)
    gemm_layer<IN_N, R_N, 8, true, false, false, true>
        <<<dim3(E_N * (R_N / 32) * 8), dim3(256), 0, stream>>>(
            nullptr, x, W1, d1, P1, nullptr);
    reduce_ks_bf16<8, B_N * R_N>
        <<<dim3(E_N * B_N * R_N / 256), dim3(256), 0, stream>>>(P1, h1b);

    // L2: K=512, N=4096, relu -> bf16
    gemm_layer<R_N, H_N, 1, false, true, true, false>
        <<<dim3(E_N * (H_N / 32)), dim3(256), 0, stream>>>(
            h1b, nullptr, W2, d2, nullptr, h2b);

    // L3: K=4096, N=512, KS=8
    gemm_layer<H_N, R_N, 8, false, false, false, false>
        <<<dim3(E_N * (R_N / 32) * 8), dim3(256), 0, stream>>>(
            h2b, nullptr, W3, d3, P3, nullptr);
    reduce_ks_bf16<8, B_N * R_N>
        <<<dim3(E_N * B_N * R_N / 256), dim3(256), 0, stream>>>(P3, h3b);

    // L4: K=512, N=4096 -> P4 f32
    gemm_layer<R_N, OUT_N, 1, false, false, false, false>
        <<<dim3(E_N * (OUT_N / 32)), dim3(256), 0, stream>>>(
            h3b, nullptr, W4, d4, P4, nullptr);

    // out = sum_e scores[e] * P4[e]
    reduce_experts<<<dim3(B_N * OUT_N / 2 / 256), dim3(256), 0, stream>>>(P4, scores, out);
}